// Round 4
// baseline (707.273 us; speedup 1.0000x reference)
//
#include <hip/hip_runtime.h>

// segment_sum: out[receivers[e], :] += edges[e, :]
// E=1,600,000 edges, D_EDGE=50, N_NODES=100,000, fp32.
//
// Strategy: counting-sort edge ids by receiver each call (ws scratch), then
// gather-sum per node with one 64-lane wave (lanes 0..49 = features).
// Removes all fp32 atomics on the 320MB edge array (R1 atomic version was
// bound at ~214G atomics/s, WRITE_SIZE 378MB from atomic write-through).
//
// R2/R3 hit "container failed twice" with no counters. This revision adds
// cost-free bounds clamps on every indirect index (no GPU page fault is
// possible from this code) and replaces the serial 98-iter block-sum scan
// with an LDS scan. If the container dies again, it is provably infra.

#define N_EDGES   1600000
#define D_EDGE    50
#define N_NODES   100000

// ws layout (bytes)
#define CNT_OFF   0u                  // 100000 ints  (cleared each call)
#define OFF_OFF   400000u             // 100000 ints  (exclusive prefix -> end cursors)
#define BSUM_OFF  800000u             // 128 ints     (block sums for scan)
#define EIDS_OFF  800512u             // 1,600,000 ints (edge ids sorted by receiver)
#define WS_NEEDED (800512u + 6400000u)

// ---------------- phase A: histogram ----------------
__global__ __launch_bounds__(256) void hist_kernel(
    const int* __restrict__ receivers, int* __restrict__ cnt)
{
    int e = blockIdx.x * 256 + threadIdx.x;
    if (e < N_EDGES) {
        int r = receivers[e];
        r = (r < 0) ? 0 : ((r >= N_NODES) ? N_NODES - 1 : r);   // defensive clamp
        atomicAdd(&cnt[r], 1);
    }
}

// ---------------- phase B1: per-block scan (1024 elems/block) ----------------
__global__ __launch_bounds__(256) void scan_blocks_kernel(
    const int* __restrict__ cnt, int* __restrict__ off, int* __restrict__ bsum)
{
    __shared__ int s[256];
    int t = threadIdx.x;
    int base = blockIdx.x * 1024 + t * 4;
    int v0 = (base + 0 < N_NODES) ? cnt[base + 0] : 0;
    int v1 = (base + 1 < N_NODES) ? cnt[base + 1] : 0;
    int v2 = (base + 2 < N_NODES) ? cnt[base + 2] : 0;
    int v3 = (base + 3 < N_NODES) ? cnt[base + 3] : 0;
    int tsum = v0 + v1 + v2 + v3;
    s[t] = tsum;
    __syncthreads();
    // Hillis-Steele inclusive scan over 256 thread-sums (uniform loop)
    for (int ofs = 1; ofs < 256; ofs <<= 1) {
        int x = (t >= ofs) ? s[t - ofs] : 0;
        __syncthreads();
        s[t] += x;
        __syncthreads();
    }
    int excl = s[t] - tsum;   // exclusive prefix of this thread's 4 elems
    if (base + 0 < N_NODES) off[base + 0] = excl;
    if (base + 1 < N_NODES) off[base + 1] = excl + v0;
    if (base + 2 < N_NODES) off[base + 2] = excl + v0 + v1;
    if (base + 3 < N_NODES) off[base + 3] = excl + v0 + v1 + v2;
    if (t == 255) bsum[blockIdx.x] = s[255];
}

// ---------------- phase B2: exclusive-scan the 98 block sums (LDS scan) ----------------
__global__ __launch_bounds__(128) void scan_bsum_kernel(int* __restrict__ bsum, int n)
{
    __shared__ int s[128];
    int t = threadIdx.x;
    int v = (t < n) ? bsum[t] : 0;
    s[t] = v;
    __syncthreads();
    for (int ofs = 1; ofs < 128; ofs <<= 1) {
        int x = (t >= ofs) ? s[t - ofs] : 0;
        __syncthreads();
        s[t] += x;
        __syncthreads();
    }
    if (t < n) bsum[t] = s[t] - v;   // exclusive
}

// ---------------- phase B3: add block offsets ----------------
__global__ __launch_bounds__(256) void add_offsets_kernel(
    int* __restrict__ off, const int* __restrict__ bsum)
{
    int i = blockIdx.x * 256 + threadIdx.x;
    if (i < N_NODES) off[i] += bsum[i >> 10];
}

// ---------------- phase C: scatter edge ids into sorted order ----------------
// Turns off[i] (exclusive start) into off[i] (end position) via atomic cursors.
__global__ __launch_bounds__(256) void scatter_ids_kernel(
    const int* __restrict__ receivers, int* __restrict__ off, int* __restrict__ eids)
{
    int e = blockIdx.x * 256 + threadIdx.x;
    if (e < N_EDGES) {
        int r = receivers[e];
        r = (r < 0) ? 0 : ((r >= N_NODES) ? N_NODES - 1 : r);   // defensive clamp
        int pos = atomicAdd(&off[r], 1);
        if (pos >= 0 && pos < N_EDGES) eids[pos] = e;           // defensive bound
    }
}

// ---------------- phase D: gather-sum, one wave per node ----------------
// After phase C, off[i] = end(i); start(i) = (i==0) ? 0 : off[i-1].
__global__ __launch_bounds__(256) void gather_kernel(
    const float* __restrict__ edges, const int* __restrict__ off,
    const int* __restrict__ eids, float* __restrict__ out)
{
    int wave = blockIdx.x * 4 + (threadIdx.x >> 6);   // node id
    int lane = threadIdx.x & 63;
    if (wave >= N_NODES) return;
    int start = (wave == 0) ? 0 : off[wave - 1];
    int end   = off[wave];
    start = (start < 0) ? 0 : start;                   // defensive
    end   = (end > N_EDGES) ? N_EDGES : end;           // defensive
    int l = (lane < D_EDGE) ? lane : 0;   // inactive lanes read lane 0 (coalesced, harmless)
    float acc = 0.0f;
    int j = start;
    for (; j + 1 < end; j += 2) {
        int e0 = eids[j];
        int e1 = eids[j + 1];
        e0 = (e0 < 0 || e0 >= N_EDGES) ? 0 : e0;       // defensive
        e1 = (e1 < 0 || e1 >= N_EDGES) ? 0 : e1;       // defensive
        float a = edges[e0 * D_EDGE + l];
        float b = edges[e1 * D_EDGE + l];
        acc += a + b;
    }
    if (j < end) {
        int e0 = eids[j];
        e0 = (e0 < 0 || e0 >= N_EDGES) ? 0 : e0;       // defensive
        acc += edges[e0 * D_EDGE + l];
    }
    if (lane < D_EDGE) out[wave * D_EDGE + lane] = acc;
}

// ---------------- fallback (R1): element-wise atomics ----------------
__global__ __launch_bounds__(256) void scatter_add_kernel(
    const float* __restrict__ edges, const int* __restrict__ receivers,
    float* __restrict__ out)
{
    long long t = (long long)blockIdx.x * blockDim.x + threadIdx.x;
    if (t >= (long long)N_EDGES * D_EDGE) return;
    int e = (int)(t / D_EDGE);
    int d = (int)(t - (long long)e * D_EDGE);
    int r = receivers[e];
    r = (r < 0) ? 0 : ((r >= N_NODES) ? N_NODES - 1 : r);
    atomicAdd(&out[(long long)r * D_EDGE + d], edges[t]);
}

extern "C" void kernel_launch(void* const* d_in, const int* in_sizes, int n_in,
                              void* d_out, int out_size, void* d_ws, size_t ws_size,
                              hipStream_t stream) {
    const float* edges     = (const float*)d_in[1];
    const int*   receivers = (const int*)d_in[2];
    float*       out       = (float*)d_out;

    if (ws_size < WS_NEEDED || d_ws == nullptr) {
        // fallback: correct but slower
        hipMemsetAsync(d_out, 0, (size_t)out_size * sizeof(float), stream);
        const long long total = (long long)N_EDGES * D_EDGE;
        const int grid = (int)((total + 255) / 256);
        scatter_add_kernel<<<grid, 256, 0, stream>>>(edges, receivers, out);
        return;
    }

    char* ws   = (char*)d_ws;
    int*  cnt  = (int*)(ws + CNT_OFF);
    int*  off  = (int*)(ws + OFF_OFF);
    int*  bsum = (int*)(ws + BSUM_OFF);
    int*  eids = (int*)(ws + EIDS_OFF);

    // zero the histogram (ws is re-poisoned to 0xAA before every call)
    hipMemsetAsync(cnt, 0, N_NODES * sizeof(int), stream);

    const int egrid = (N_EDGES + 255) / 256;                 // 6250
    hist_kernel<<<egrid, 256, 0, stream>>>(receivers, cnt);

    const int sblocks = (N_NODES + 1023) / 1024;             // 98
    scan_blocks_kernel<<<sblocks, 256, 0, stream>>>(cnt, off, bsum);
    scan_bsum_kernel<<<1, 128, 0, stream>>>(bsum, sblocks);
    add_offsets_kernel<<<(N_NODES + 255) / 256, 256, 0, stream>>>(off, bsum);

    scatter_ids_kernel<<<egrid, 256, 0, stream>>>(receivers, off, eids);

    // one wave per node, 4 waves per block
    gather_kernel<<<(N_NODES + 3) / 4, 256, 0, stream>>>(edges, off, eids, out);
}

// Round 5
// 660.799 us; speedup vs baseline: 1.0703x; 1.0703x over previous
//
#include <hip/hip_runtime.h>

// segment_sum: out[receivers[e], :] += edges[e, :]
// E=1,600,000 edges, D_EDGE=50, N_NODES=100,000, fp32.
//
// Counting-sort edge ids by receiver (ws scratch), then gather-sum per node,
// one 64-lane wave per node (lanes 0..49 = features).
//
// R4: gather was latency-bound (1.45 TB/s, 18% peak) — only 2 row loads in
// flight per wave. R5: 8-deep pipelined gather (8 independent 200B row loads
// in flight), masked 8-wide tail. Phases unchanged; if total stays high the
// expensive phase will now appear in top-5 (gather should drop to ~70us).

#define N_EDGES   1600000
#define D_EDGE    50
#define N_NODES   100000

// ws layout (bytes)
#define CNT_OFF   0u                  // 100000 ints  (cleared each call)
#define OFF_OFF   400000u             // 100000 ints  (prefix -> end cursors)
#define BSUM_OFF  800000u             // 128 ints     (block sums for scan)
#define EIDS_OFF  800512u             // 1,600,000 ints (edge ids sorted by receiver)
#define WS_NEEDED (800512u + 6400000u)

// ---------------- phase A: histogram ----------------
__global__ __launch_bounds__(256) void hist_kernel(
    const int* __restrict__ receivers, int* __restrict__ cnt)
{
    int e = blockIdx.x * 256 + threadIdx.x;
    if (e < N_EDGES) {
        int r = receivers[e];
        r = (r < 0) ? 0 : ((r >= N_NODES) ? N_NODES - 1 : r);   // defensive clamp
        atomicAdd(&cnt[r], 1);
    }
}

// ---------------- phase B1: per-block scan (1024 elems/block) ----------------
__global__ __launch_bounds__(256) void scan_blocks_kernel(
    const int* __restrict__ cnt, int* __restrict__ off, int* __restrict__ bsum)
{
    __shared__ int s[256];
    int t = threadIdx.x;
    int base = blockIdx.x * 1024 + t * 4;
    int v0 = (base + 0 < N_NODES) ? cnt[base + 0] : 0;
    int v1 = (base + 1 < N_NODES) ? cnt[base + 1] : 0;
    int v2 = (base + 2 < N_NODES) ? cnt[base + 2] : 0;
    int v3 = (base + 3 < N_NODES) ? cnt[base + 3] : 0;
    int tsum = v0 + v1 + v2 + v3;
    s[t] = tsum;
    __syncthreads();
    for (int ofs = 1; ofs < 256; ofs <<= 1) {
        int x = (t >= ofs) ? s[t - ofs] : 0;
        __syncthreads();
        s[t] += x;
        __syncthreads();
    }
    int excl = s[t] - tsum;
    if (base + 0 < N_NODES) off[base + 0] = excl;
    if (base + 1 < N_NODES) off[base + 1] = excl + v0;
    if (base + 2 < N_NODES) off[base + 2] = excl + v0 + v1;
    if (base + 3 < N_NODES) off[base + 3] = excl + v0 + v1 + v2;
    if (t == 255) bsum[blockIdx.x] = s[255];
}

// ---------------- phase B2: exclusive-scan the 98 block sums ----------------
__global__ __launch_bounds__(128) void scan_bsum_kernel(int* __restrict__ bsum, int n)
{
    __shared__ int s[128];
    int t = threadIdx.x;
    int v = (t < n) ? bsum[t] : 0;
    s[t] = v;
    __syncthreads();
    for (int ofs = 1; ofs < 128; ofs <<= 1) {
        int x = (t >= ofs) ? s[t - ofs] : 0;
        __syncthreads();
        s[t] += x;
        __syncthreads();
    }
    if (t < n) bsum[t] = s[t] - v;   // exclusive
}

// ---------------- phase B3: add block offsets ----------------
__global__ __launch_bounds__(256) void add_offsets_kernel(
    int* __restrict__ off, const int* __restrict__ bsum)
{
    int i = blockIdx.x * 256 + threadIdx.x;
    if (i < N_NODES) off[i] += bsum[i >> 10];
}

// ---------------- phase C: scatter edge ids into sorted order ----------------
// Turns off[i] (exclusive start) into off[i] (end position) via atomic cursors.
__global__ __launch_bounds__(256) void scatter_ids_kernel(
    const int* __restrict__ receivers, int* __restrict__ off, int* __restrict__ eids)
{
    int e = blockIdx.x * 256 + threadIdx.x;
    if (e < N_EDGES) {
        int r = receivers[e];
        r = (r < 0) ? 0 : ((r >= N_NODES) ? N_NODES - 1 : r);   // defensive clamp
        int pos = atomicAdd(&off[r], 1);
        if (pos >= 0 && pos < N_EDGES) eids[pos] = e;           // defensive bound
    }
}

// ---------------- phase D: gather-sum, one wave per node, 8-deep pipeline ----
// After phase C, off[i] = end(i); start(i) = (i==0) ? 0 : off[i-1].
__global__ __launch_bounds__(256) void gather_kernel(
    const float* __restrict__ edges, const int* __restrict__ off,
    const int* __restrict__ eids, float* __restrict__ out)
{
    int wave = blockIdx.x * 4 + (threadIdx.x >> 6);   // node id
    int lane = threadIdx.x & 63;
    if (wave >= N_NODES) return;
    int start = (wave == 0) ? 0 : off[wave - 1];
    int end   = off[wave];
    start = (start < 0) ? 0 : start;                   // defensive
    end   = (end > N_EDGES) ? N_EDGES : end;           // defensive

    if (end <= start) {                                // empty node
        if (lane < D_EDGE) out[wave * D_EDGE + lane] = 0.0f;
        return;
    }

    int l = (lane < D_EDGE) ? lane : 0;   // inactive lanes alias lane 0 (same line)
    float acc = 0.0f;
    int last = end - 1;

    // 8-wide pipelined loop, masked tail: always issue 8 independent row
    // loads (duplicates for the tail hit the same cache line — ~free),
    // zero-mask the surplus contributions.
    for (int j = start; j < end; j += 8) {
        int i0 = j + 0, i1 = j + 1, i2 = j + 2, i3 = j + 3;
        int i4 = j + 4, i5 = j + 5, i6 = j + 6, i7 = j + 7;
        float m1 = (i1 <= last) ? 1.0f : 0.0f;
        float m2 = (i2 <= last) ? 1.0f : 0.0f;
        float m3 = (i3 <= last) ? 1.0f : 0.0f;
        float m4 = (i4 <= last) ? 1.0f : 0.0f;
        float m5 = (i5 <= last) ? 1.0f : 0.0f;
        float m6 = (i6 <= last) ? 1.0f : 0.0f;
        float m7 = (i7 <= last) ? 1.0f : 0.0f;
        i1 = (i1 <= last) ? i1 : last;
        i2 = (i2 <= last) ? i2 : last;
        i3 = (i3 <= last) ? i3 : last;
        i4 = (i4 <= last) ? i4 : last;
        i5 = (i5 <= last) ? i5 : last;
        i6 = (i6 <= last) ? i6 : last;
        i7 = (i7 <= last) ? i7 : last;
        // 8 wave-uniform id loads (broadcast transactions)
        int e0 = eids[i0], e1 = eids[i1], e2 = eids[i2], e3 = eids[i3];
        int e4 = eids[i4], e5 = eids[i5], e6 = eids[i6], e7 = eids[i7];
        // defensive clamps (no page fault possible)
        e0 = (e0 < 0 || e0 >= N_EDGES) ? 0 : e0;
        e1 = (e1 < 0 || e1 >= N_EDGES) ? 0 : e1;
        e2 = (e2 < 0 || e2 >= N_EDGES) ? 0 : e2;
        e3 = (e3 < 0 || e3 >= N_EDGES) ? 0 : e3;
        e4 = (e4 < 0 || e4 >= N_EDGES) ? 0 : e4;
        e5 = (e5 < 0 || e5 >= N_EDGES) ? 0 : e5;
        e6 = (e6 < 0 || e6 >= N_EDGES) ? 0 : e6;
        e7 = (e7 < 0 || e7 >= N_EDGES) ? 0 : e7;
        // 8 independent 200B row loads in flight
        float a0 = edges[e0 * D_EDGE + l];
        float a1 = edges[e1 * D_EDGE + l];
        float a2 = edges[e2 * D_EDGE + l];
        float a3 = edges[e3 * D_EDGE + l];
        float a4 = edges[e4 * D_EDGE + l];
        float a5 = edges[e5 * D_EDGE + l];
        float a6 = edges[e6 * D_EDGE + l];
        float a7 = edges[e7 * D_EDGE + l];
        acc += ((a0 + m1 * a1) + (m2 * a2 + m3 * a3))
             + ((m4 * a4 + m5 * a5) + (m6 * a6 + m7 * a7));
    }
    if (lane < D_EDGE) out[wave * D_EDGE + lane] = acc;
}

// ---------------- fallback (R1): element-wise atomics ----------------
__global__ __launch_bounds__(256) void scatter_add_kernel(
    const float* __restrict__ edges, const int* __restrict__ receivers,
    float* __restrict__ out)
{
    long long t = (long long)blockIdx.x * blockDim.x + threadIdx.x;
    if (t >= (long long)N_EDGES * D_EDGE) return;
    int e = (int)(t / D_EDGE);
    int d = (int)(t - (long long)e * D_EDGE);
    int r = receivers[e];
    r = (r < 0) ? 0 : ((r >= N_NODES) ? N_NODES - 1 : r);
    atomicAdd(&out[(long long)r * D_EDGE + d], edges[t]);
}

extern "C" void kernel_launch(void* const* d_in, const int* in_sizes, int n_in,
                              void* d_out, int out_size, void* d_ws, size_t ws_size,
                              hipStream_t stream) {
    const float* edges     = (const float*)d_in[1];
    const int*   receivers = (const int*)d_in[2];
    float*       out       = (float*)d_out;

    if (ws_size < WS_NEEDED || d_ws == nullptr) {
        hipMemsetAsync(d_out, 0, (size_t)out_size * sizeof(float), stream);
        const long long total = (long long)N_EDGES * D_EDGE;
        const int grid = (int)((total + 255) / 256);
        scatter_add_kernel<<<grid, 256, 0, stream>>>(edges, receivers, out);
        return;
    }

    char* ws   = (char*)d_ws;
    int*  cnt  = (int*)(ws + CNT_OFF);
    int*  off  = (int*)(ws + OFF_OFF);
    int*  bsum = (int*)(ws + BSUM_OFF);
    int*  eids = (int*)(ws + EIDS_OFF);

    hipMemsetAsync(cnt, 0, N_NODES * sizeof(int), stream);

    const int egrid = (N_EDGES + 255) / 256;                 // 6250
    hist_kernel<<<egrid, 256, 0, stream>>>(receivers, cnt);

    const int sblocks = (N_NODES + 1023) / 1024;             // 98
    scan_blocks_kernel<<<sblocks, 256, 0, stream>>>(cnt, off, bsum);
    scan_bsum_kernel<<<1, 128, 0, stream>>>(bsum, sblocks);
    add_offsets_kernel<<<(N_NODES + 255) / 256, 256, 0, stream>>>(off, bsum);

    scatter_ids_kernel<<<egrid, 256, 0, stream>>>(receivers, off, eids);

    gather_kernel<<<(N_NODES + 3) / 4, 256, 0, stream>>>(edges, off, eids, out);
}